// Round 9
// baseline (650.837 us; speedup 1.0000x reference)
//
#include <hip/hip_runtime.h>

// Problem constants (from reference)
#define C_IMG 16
#define GRIDSZ 128
#define VOL (GRIDSZ * GRIDSZ * GRIDSZ)
#define SLOPE 0.3f
#define SCALE 0.1f
#define EPB 4096         // edges per k_bucket block
#define HEPB 16384       // edges per k_hist block
#define BIN_CAP 16384    // max edges per 512-vertex bucket (mean 8192, sd ~90)

// bf16 helpers (manual, RNE pack / shift unpack)
__device__ __forceinline__ unsigned int bf16_pack2(float a, float b) {
    unsigned int ua = __float_as_uint(a);
    ua = (ua + 0x7FFFu + ((ua >> 16) & 1u)) >> 16;
    unsigned int ub = __float_as_uint(b);
    ub = (ub + 0x7FFFu + ((ub >> 16) & 1u)) >> 16;
    return ua | (ub << 16);
}
__device__ __forceinline__ float bf_lo(unsigned int u) { return __uint_as_float(u << 16); }
__device__ __forceinline__ float bf_hi(unsigned int u) { return __uint_as_float(u & 0xFFFF0000u); }

// ---------------------------------------------------------------------------
// Per-block LDS histogram of dst buckets (dst>>9), one global atomic per
// (block, bucket).
__global__ __launch_bounds__(256) void k_hist(const int* __restrict__ edst,
                                              int* __restrict__ bucketCount, int ne) {
    __shared__ int h[256];
    const int tid = threadIdx.x;
    h[tid] = 0;
    __syncthreads();
    const int base = blockIdx.x * HEPB;
    const int n = min(HEPB, ne - base);
    for (int i = tid; i < n; i += 256)
        atomicAdd(&h[((unsigned)edst[base + i]) >> 9], 1);
    __syncthreads();
    if (h[tid]) atomicAdd(&bucketCount[tid], h[tid]);
}

// Exclusive scan of <=256 bucket counts -> bucketBase (+ cursors); also sets
// bucketBase[np] = ne and rowStart[nv] = ne.
__global__ __launch_bounds__(256) void k_scan256(const int* __restrict__ bucketCount,
                                                 int* __restrict__ bucketBase,
                                                 int* __restrict__ bucketCursor,
                                                 int* __restrict__ rowStart,
                                                 int np, int nv, int ne) {
    __shared__ int buf[256];
    const int tid = threadIdx.x;
    const int v = (tid < np) ? bucketCount[tid] : 0;
    buf[tid] = v;
    __syncthreads();
    #pragma unroll
    for (int off = 1; off < 256; off <<= 1) {
        int t = (tid >= off) ? buf[tid - off] : 0;
        __syncthreads();
        buf[tid] += t;
        __syncthreads();
    }
    const int excl = buf[tid] - v;
    bucketBase[tid] = excl;
    bucketCursor[tid] = excl;
    if (tid == 0) {
        bucketBase[np] = ne;
        rowStart[nv] = ne;
    }
}

// Bucketing pass: group (dst,src) pairs by dst>>9 into per-bucket global
// regions with dense (coalesced-run) writes. LDS-staged local grouping.
__global__ __launch_bounds__(256) void k_bucket(const int* __restrict__ esrc,
                                                const int* __restrict__ edst,
                                                int* __restrict__ bucketCursor,
                                                uint2* __restrict__ pairs, int ne) {
    __shared__ unsigned int hist[256];
    __shared__ unsigned int pref[256];
    __shared__ unsigned int curs[256];
    __shared__ unsigned int gbase[256];
    __shared__ uint2 stage[EPB];
    const int tid = threadIdx.x;
    const int base = blockIdx.x * EPB;
    const int n = min(EPB, ne - base);
    hist[tid] = 0;
    __syncthreads();
    for (int i = tid; i < n; i += 256)
        atomicAdd(&hist[((unsigned)edst[base + i]) >> 9], 1u);
    __syncthreads();
    const unsigned int h = hist[tid];
    pref[tid] = h;
    __syncthreads();
    #pragma unroll
    for (int off = 1; off < 256; off <<= 1) {
        unsigned int t = (tid >= off) ? pref[tid - off] : 0;
        __syncthreads();
        pref[tid] += t;
        __syncthreads();
    }
    const unsigned int excl = pref[tid] - h;
    gbase[tid] = h ? (unsigned int)atomicAdd(&bucketCursor[tid], (int)h) : 0u;
    __syncthreads();
    pref[tid] = excl;
    curs[tid] = excl;
    __syncthreads();
    for (int i = tid; i < n; i += 256) {
        int d = edst[base + i];
        int s = esrc[base + i];
        unsigned int p = atomicAdd(&curs[((unsigned)d) >> 9], 1u);
        stage[p] = make_uint2((unsigned)d, (unsigned)s);
    }
    __syncthreads();
    for (int i = tid; i < n; i += 256) {
        uint2 pr = stage[i];
        unsigned int b = pr.x >> 9;
        pairs[gbase[b] + (unsigned)i - pref[b]] = pr;
    }
}

// Within-bucket: per-vertex degree + rowStart + invdeg in LDS, then scatter
// srcs via LDS cursors, flush coalesced. One block per 512-vtx bucket.
__global__ __launch_bounds__(256) void k_binsort(const uint2* __restrict__ pairs,
                                                 const int* __restrict__ bucketBase,
                                                 int* __restrict__ rowStart,
                                                 float* __restrict__ invdeg,
                                                 int* __restrict__ csrSrc, int nv) {
    __shared__ int deg_s[512];
    __shared__ int rs_s[512];
    __shared__ int cur_s[512];
    __shared__ int scan_s[256];
    __shared__ int outbuf[BIN_CAP];
    const int tid = threadIdx.x;
    const int b = blockIdx.x;
    const int vbase = b << 9;
    if (vbase >= nv) return;
    const int nvb = min(512, nv - vbase);
    const int gs = bucketBase[b];
    const int ge = bucketBase[b + 1];
    const int count = ge - gs;
    deg_s[tid] = 0;
    deg_s[tid + 256] = 0;
    __syncthreads();
    for (int i = tid; i < count; i += 256) {
        uint2 p = pairs[gs + i];
        atomicAdd(&deg_s[p.x - (unsigned)vbase], 1);
    }
    __syncthreads();
    const int d0 = deg_s[2 * tid];
    const int d1 = deg_s[2 * tid + 1];
    const int ps = d0 + d1;
    scan_s[tid] = ps;
    __syncthreads();
    #pragma unroll
    for (int off = 1; off < 256; off <<= 1) {
        int t = (tid >= off) ? scan_s[tid - off] : 0;
        __syncthreads();
        scan_s[tid] += t;
        __syncthreads();
    }
    const int epair = scan_s[tid] - ps;
    rs_s[2 * tid] = epair;
    rs_s[2 * tid + 1] = epair + d0;
    cur_s[2 * tid] = epair;
    cur_s[2 * tid + 1] = epair + d0;
    #pragma unroll
    for (int u = 0; u < 2; ++u) {
        int idx = 2 * tid + u;
        if (idx < nvb) {
            rowStart[vbase + idx] = gs + rs_s[idx];
            int d = deg_s[idx];
            invdeg[vbase + idx] = 1.0f / (float)(d > 1 ? d : 1);
        }
    }
    __syncthreads();
    if (count <= BIN_CAP) {
        for (int i = tid; i < count; i += 256) {
            uint2 p = pairs[gs + i];
            int pos = atomicAdd(&cur_s[p.x - (unsigned)vbase], 1);
            outbuf[pos] = (int)p.y;
        }
        __syncthreads();
        for (int i = tid; i < count; i += 256) csrSrc[gs + i] = outbuf[i];
    } else {
        for (int i = tid; i < count; i += 256) {
            uint2 p = pairs[gs + i];
            int pos = atomicAdd(&cur_s[p.x - (unsigned)vbase], 1);
            csrSrc[gs + pos] = (int)p.y;
        }
    }
}

// ---------------------------------------------------------------------------
// Image transpose: img[16][128][128][128] fp32 -> timg[x][y][z][16] bf16.
__global__ __launch_bounds__(256) void k_transpose(const float* __restrict__ img,
                                                   unsigned int* __restrict__ timg) {
    const int t = blockIdx.x * 256 + threadIdx.x;
    const int q  = t & 3;
    const int z4 = (t >> 2) & 31;
    const int xy = t >> 7;
    const int z0 = z4 * 4;
    const int c0 = q * 4;
    const size_t base = (size_t)xy * GRIDSZ + z0;
    float4 v0 = *(const float4*)(img + (size_t)(c0 + 0) * VOL + base);
    float4 v1 = *(const float4*)(img + (size_t)(c0 + 1) * VOL + base);
    float4 v2 = *(const float4*)(img + (size_t)(c0 + 2) * VOL + base);
    float4 v3 = *(const float4*)(img + (size_t)(c0 + 3) * VOL + base);
    #pragma unroll
    for (int j = 0; j < 4; ++j) {
        float f0 = (j == 0) ? v0.x : (j == 1) ? v0.y : (j == 2) ? v0.z : v0.w;
        float f1 = (j == 0) ? v1.x : (j == 1) ? v1.y : (j == 2) ? v1.z : v1.w;
        float f2 = (j == 0) ? v2.x : (j == 1) ? v2.y : (j == 2) ? v2.z : v2.w;
        float f3 = (j == 0) ? v3.x : (j == 1) ? v3.y : (j == 2) ? v3.z : v3.w;
        uint2 o;
        o.x = bf16_pack2(f0, f1);
        o.y = bf16_pack2(f2, f3);
        *(uint2*)(timg + (size_t)(xy * GRIDSZ + z0 + j) * 8 + q * 2) = o;
    }
}

// ---------------------------------------------------------------------------
// Trilinear sample -> bf16 feats rows, stride 16 uints (32 bf16 cols):
// cols 0..15 = channels, 16..18 = verts/128, 19..31 = 0.
__global__ __launch_bounds__(256) void k_sample(const unsigned int* __restrict__ timg,
                                                const float* __restrict__ verts,
                                                unsigned int* __restrict__ feats, int nv) {
    int t = blockIdx.x * 256 + threadIdx.x;
    int v = t >> 1;
    int q = t & 1;
    if (v >= nv) return;
    float px = verts[v * 3 + 0];
    float py = verts[v * 3 + 1];
    float pz = verts[v * 3 + 2];
    float cx = fminf(fmaxf(px, 0.0f), 127.0f);
    float cy = fminf(fmaxf(py, 0.0f), 127.0f);
    float cz = fminf(fmaxf(pz, 0.0f), 127.0f);
    float fx = floorf(cx), fy = floorf(cy), fz = floorf(cz);
    int x0 = (int)fx, y0 = (int)fy, z0 = (int)fz;
    int x1 = min(x0 + 1, 127), y1 = min(y0 + 1, 127), z1 = min(z0 + 1, 127);
    float wx = cx - fx, wy = cy - fy, wz = cz - fz;
    const int qo = q * 4;
    #define LD(X, Y, Z) (*(const uint4*)(timg + ((size_t)((((X) << 7) + (Y)) << 7) + (size_t)(Z)) * 8 + qo))
    uint4 f000 = LD(x0, y0, z0), f001 = LD(x0, y0, z1);
    uint4 f010 = LD(x0, y1, z0), f011 = LD(x0, y1, z1);
    uint4 f100 = LD(x1, y0, z0), f101 = LD(x1, y0, z1);
    uint4 f110 = LD(x1, y1, z0), f111 = LD(x1, y1, z1);
    #undef LD
    float r[8];
    const unsigned int* a000 = (const unsigned int*)&f000;
    const unsigned int* a001 = (const unsigned int*)&f001;
    const unsigned int* a010 = (const unsigned int*)&f010;
    const unsigned int* a011 = (const unsigned int*)&f011;
    const unsigned int* a100 = (const unsigned int*)&f100;
    const unsigned int* a101 = (const unsigned int*)&f101;
    const unsigned int* a110 = (const unsigned int*)&f110;
    const unsigned int* a111 = (const unsigned int*)&f111;
    #pragma unroll
    for (int u = 0; u < 4; ++u) {
        float c00l = bf_lo(a000[u]) * (1.f - wz) + bf_lo(a001[u]) * wz;
        float c01l = bf_lo(a010[u]) * (1.f - wz) + bf_lo(a011[u]) * wz;
        float c10l = bf_lo(a100[u]) * (1.f - wz) + bf_lo(a101[u]) * wz;
        float c11l = bf_lo(a110[u]) * (1.f - wz) + bf_lo(a111[u]) * wz;
        r[2 * u] = (c00l * (1.f - wy) + c01l * wy) * (1.f - wx) +
                   (c10l * (1.f - wy) + c11l * wy) * wx;
        float c00h = bf_hi(a000[u]) * (1.f - wz) + bf_hi(a001[u]) * wz;
        float c01h = bf_hi(a010[u]) * (1.f - wz) + bf_hi(a011[u]) * wz;
        float c10h = bf_hi(a100[u]) * (1.f - wz) + bf_hi(a101[u]) * wz;
        float c11h = bf_hi(a110[u]) * (1.f - wz) + bf_hi(a111[u]) * wz;
        r[2 * u + 1] = (c00h * (1.f - wy) + c01h * wy) * (1.f - wx) +
                       (c10h * (1.f - wy) + c11h * wy) * wx;
    }
    unsigned int* row = feats + (size_t)v * 16;
    uint4 o;
    o.x = bf16_pack2(r[0], r[1]); o.y = bf16_pack2(r[2], r[3]);
    o.z = bf16_pack2(r[4], r[5]); o.w = bf16_pack2(r[6], r[7]);
    *(uint4*)(row + q * 4) = o;
    if (q == 0) {
        uint4 o2;
        o2.x = bf16_pack2(px * (1.0f / 128.0f), py * (1.0f / 128.0f));
        o2.y = bf16_pack2(pz * (1.0f / 128.0f), 0.0f);
        o2.z = 0u; o2.w = 0u;
        *(uint4*)(row + 8) = o2;
        *(uint4*)(row + 12) = make_uint4(0u, 0u, 0u, 0u);
    }
}

// ---------------------------------------------------------------------------
// Fused gather + edge-conv layer. Phase A: gather this block's VPB vertices'
// neighbor sums (bf16, fp32 accum) into LDS (stride padded +2 uints -> only
// 2-way bank aliasing in phase B, which is free). Phase B: the FMA-bound
// matmul, nb from LDS. PREMUL (layer 2): epilogue also accumulates
// z = h3 @ Wn3 from the fp32 accumulators via LDS float atomics.
template <int CIN, int COUT, int SXU, bool RELU, bool REMAP0, bool PREMUL>
__global__ __launch_bounds__(256) void k_gconv(const unsigned int* __restrict__ x,
                                               const int* __restrict__ rowStart,
                                               const int* __restrict__ csrSrc,
                                               const float* __restrict__ invdeg,
                                               const float* __restrict__ Ws,
                                               const float* __restrict__ Wn,
                                               const float* __restrict__ b,
                                               const float* __restrict__ wn3,
                                               unsigned int* __restrict__ out,
                                               unsigned int* __restrict__ z, int nv) {
    constexpr int GR = COUT / 8;
    constexpr int VPT = 4;
    constexpr int TPB = 256;
    constexpr int VPB = (TPB / GR) * VPT;
    constexpr int KP = (CIN + 3) & ~3;
    constexpr int SOU = COUT / 2;
    constexpr int NCH = SXU / 4;
    constexpr int SP = SXU + 2;          // padded LDS stride (uints)
    __shared__ float ws_s[KP * COUT];
    __shared__ float wn_s[KP * COUT];
    __shared__ unsigned int nb_s[VPB * SP];
    __shared__ float z_s[PREMUL ? VPB * 4 : 4];
    __shared__ float wn3_s[PREMUL ? 192 : 4];

    const int tid = threadIdx.x;
    for (int i = tid; i < KP * COUT; i += TPB) {
        int k = i / COUT, c = i - k * COUT;
        float vs = 0.f, vn = 0.f;
        if (k < CIN) {
            int sr = REMAP0 ? ((k < 16) ? (k + 3) : (k - 16)) : k;
            vs = Ws[sr * COUT + c];
            vn = Wn[sr * COUT + c];
        }
        ws_s[i] = vs;
        wn_s[i] = vn;
    }
    if (PREMUL) {
        if (tid < 192) wn3_s[tid] = wn3[tid];
        for (int i = tid; i < VPB * 4; i += TPB) z_s[i] = 0.f;
    }

    const int v0 = blockIdx.x * VPB;

    // ---- Phase A: gather neighbor sums into LDS -------------------------
    for (int t = tid; t < VPB * NCH; t += TPB) {
        int vl = t / NCH;
        int ch = t - vl * NCH;
        int v = v0 + vl;
        float a0 = 0.f, a1 = 0.f, a2 = 0.f, a3 = 0.f, a4 = 0.f, a5 = 0.f, a6 = 0.f, a7 = 0.f;
        if (v < nv) {
            int beg = rowStart[v];
            int end = rowStart[v + 1];
            for (int j = beg; j < end; ++j) {
                int s = csrSrc[j];
                uint4 q = ((const uint4*)(x + (size_t)s * SXU))[ch];
                a0 += bf_lo(q.x); a1 += bf_hi(q.x);
                a2 += bf_lo(q.y); a3 += bf_hi(q.y);
                a4 += bf_lo(q.z); a5 += bf_hi(q.z);
                a6 += bf_lo(q.w); a7 += bf_hi(q.w);
            }
        }
        unsigned int* dst = nb_s + vl * SP + ch * 4;
        *(uint2*)(dst + 0) = make_uint2(bf16_pack2(a0, a1), bf16_pack2(a2, a3));
        *(uint2*)(dst + 2) = make_uint2(bf16_pack2(a4, a5), bf16_pack2(a6, a7));
    }
    __syncthreads();

    // ---- Phase B: matmul -------------------------------------------------
    const int g = tid % GR;
    const int co = g * 8;
    const int vt = tid / GR;
    const int vl0 = vt * VPT;

    float acc_s[VPT][8], acc_n[VPT][8];
    #pragma unroll
    for (int u = 0; u < VPT; ++u)
        #pragma unroll
        for (int i = 0; i < 8; ++i) { acc_s[u][i] = 0.f; acc_n[u][i] = 0.f; }

    for (int k = 0; k < KP; k += 4) {
        uint2 xq[VPT], nq[VPT];
        #pragma unroll
        for (int u = 0; u < VPT; ++u) {
            int v = v0 + vl0 + u;
            if (v < nv) {
                xq[u] = *(const uint2*)(x + (size_t)v * SXU + (k >> 1));
                nq[u] = *(const uint2*)(nb_s + (vl0 + u) * SP + (k >> 1));
            } else {
                xq[u] = make_uint2(0u, 0u);
                nq[u] = make_uint2(0u, 0u);
            }
        }
        #pragma unroll
        for (int j = 0; j < 4; ++j) {
            const float4 wsa = *(const float4*)(ws_s + (k + j) * COUT + co);
            const float4 wsb = *(const float4*)(ws_s + (k + j) * COUT + co + 4);
            const float4 wna = *(const float4*)(wn_s + (k + j) * COUT + co);
            const float4 wnb = *(const float4*)(wn_s + (k + j) * COUT + co + 4);
            #pragma unroll
            for (int u = 0; u < VPT; ++u) {
                float xv = (j == 0) ? bf_lo(xq[u].x) : (j == 1) ? bf_hi(xq[u].x)
                         : (j == 2) ? bf_lo(xq[u].y) : bf_hi(xq[u].y);
                float nw = (j == 0) ? bf_lo(nq[u].x) : (j == 1) ? bf_hi(nq[u].x)
                         : (j == 2) ? bf_lo(nq[u].y) : bf_hi(nq[u].y);
                acc_s[u][0] += xv * wsa.x; acc_s[u][1] += xv * wsa.y;
                acc_s[u][2] += xv * wsa.z; acc_s[u][3] += xv * wsa.w;
                acc_s[u][4] += xv * wsb.x; acc_s[u][5] += xv * wsb.y;
                acc_s[u][6] += xv * wsb.z; acc_s[u][7] += xv * wsb.w;
                acc_n[u][0] += nw * wna.x; acc_n[u][1] += nw * wna.y;
                acc_n[u][2] += nw * wna.z; acc_n[u][3] += nw * wna.w;
                acc_n[u][4] += nw * wnb.x; acc_n[u][5] += nw * wnb.y;
                acc_n[u][6] += nw * wnb.z; acc_n[u][7] += nw * wnb.w;
            }
        }
    }

    #pragma unroll
    for (int u = 0; u < VPT; ++u) {
        int v = v0 + vl0 + u;
        if (v >= nv) continue;
        float id = invdeg[v];
        float r[8];
        #pragma unroll
        for (int i = 0; i < 8; ++i) {
            float t = acc_s[u][i] + acc_n[u][i] * id + b[co + i];
            r[i] = (!RELU || t >= 0.f) ? t : SLOPE * t;
        }
        uint4 o;
        o.x = bf16_pack2(r[0], r[1]); o.y = bf16_pack2(r[2], r[3]);
        o.z = bf16_pack2(r[4], r[5]); o.w = bf16_pack2(r[6], r[7]);
        *(uint4*)(out + (size_t)v * SOU + (co >> 1)) = o;
        if (PREMUL) {
            float p0 = 0.f, p1 = 0.f, p2 = 0.f;
            #pragma unroll
            for (int i = 0; i < 8; ++i) {
                p0 += r[i] * wn3_s[(co + i) * 3 + 0];
                p1 += r[i] * wn3_s[(co + i) * 3 + 1];
                p2 += r[i] * wn3_s[(co + i) * 3 + 2];
            }
            atomicAdd(&z_s[(vl0 + u) * 4 + 0], p0);
            atomicAdd(&z_s[(vl0 + u) * 4 + 1], p1);
            atomicAdd(&z_s[(vl0 + u) * 4 + 2], p2);
        }
    }

    if (PREMUL) {
        __syncthreads();
        for (int vl = tid; vl < VPB; vl += TPB) {
            int v = v0 + vl;
            if (v >= nv) continue;
            uint2 o;
            o.x = bf16_pack2(z_s[vl * 4 + 0], z_s[vl * 4 + 1]);
            o.y = bf16_pack2(z_s[vl * 4 + 2], 0.f);
            *(uint2*)(z + (size_t)v * 2) = o;
        }
    }
}

// Final (fused z-gather): out = verts + SCALE*(h3@Ws3 + gather(z)*inv_deg + b3)
__global__ __launch_bounds__(256) void k_final(const unsigned int* __restrict__ h,
                                               const unsigned int* __restrict__ z,
                                               const int* __restrict__ rowStart,
                                               const int* __restrict__ csrSrc,
                                               const float* __restrict__ invdeg,
                                               const float* __restrict__ ws,
                                               const float* __restrict__ b,
                                               const float* __restrict__ verts,
                                               float* __restrict__ out, int nv) {
    __shared__ float w_s[64 * 3];
    if (threadIdx.x < 64 * 3) w_s[threadIdx.x] = ws[threadIdx.x];
    __syncthreads();
    int v = blockIdx.x * 256 + threadIdx.x;
    if (v >= nv) return;
    float n0 = 0.f, n1 = 0.f, n2 = 0.f;
    {
        int beg = rowStart[v];
        int end = rowStart[v + 1];
        for (int j = beg; j < end; ++j) {
            int s = csrSrc[j];
            uint2 q = *(const uint2*)(z + (size_t)s * 2);
            n0 += bf_lo(q.x); n1 += bf_hi(q.x); n2 += bf_lo(q.y);
        }
    }
    const uint4* hr = (const uint4*)(h + (size_t)v * 32);
    float a0 = b[0], a1 = b[1], a2 = b[2];
    #pragma unroll
    for (int q = 0; q < 8; ++q) {
        uint4 hv = hr[q];
        float f[8] = {bf_lo(hv.x), bf_hi(hv.x), bf_lo(hv.y), bf_hi(hv.y),
                      bf_lo(hv.z), bf_hi(hv.z), bf_lo(hv.w), bf_hi(hv.w)};
        #pragma unroll
        for (int i = 0; i < 8; ++i) {
            int k = q * 8 + i;
            a0 += f[i] * w_s[k * 3 + 0];
            a1 += f[i] * w_s[k * 3 + 1];
            a2 += f[i] * w_s[k * 3 + 2];
        }
    }
    float id = invdeg[v];
    a0 += n0 * id; a1 += n1 * id; a2 += n2 * id;
    out[(size_t)v * 3 + 0] = verts[(size_t)v * 3 + 0] + SCALE * a0;
    out[(size_t)v * 3 + 1] = verts[(size_t)v * 3 + 1] + SCALE * a1;
    out[(size_t)v * 3 + 2] = verts[(size_t)v * 3 + 2] + SCALE * a2;
}

// ---------------------------------------------------------------------------
extern "C" void kernel_launch(void* const* d_in, const int* in_sizes, int n_in,
                              void* d_out, int out_size, void* d_ws, size_t ws_size,
                              hipStream_t stream) {
    const float* img   = (const float*)d_in[0];
    const float* verts = (const float*)d_in[1];
    const int*   esrc  = (const int*)d_in[2];
    const int*   edst  = (const int*)d_in[3];
    const float* ws0 = (const float*)d_in[4];
    const float* wn0 = (const float*)d_in[5];
    const float* b0  = (const float*)d_in[6];
    const float* ws1 = (const float*)d_in[7];
    const float* wn1 = (const float*)d_in[8];
    const float* b1  = (const float*)d_in[9];
    const float* ws2 = (const float*)d_in[10];
    const float* wn2 = (const float*)d_in[11];
    const float* b2  = (const float*)d_in[12];
    const float* ws3 = (const float*)d_in[13];
    const float* wn3 = (const float*)d_in[14];
    const float* b3  = (const float*)d_in[15];

    const int nv = in_sizes[1] / 3;
    const int ne = in_sizes[2];

    char* base = (char*)d_ws;
    size_t off = 0;
    auto alloc = [&](size_t bytes) -> void* {
        off = (off + 255) & ~(size_t)255;
        void* p = base + off;
        off += bytes;
        return p;
    };
    float* invdeg   = (float*)alloc((size_t)nv * 4);
    int*   rowStart = (int*)alloc((size_t)(nv + 1) * 4);
    int*   bucketCount  = (int*)alloc(256 * 4);
    int*   bucketBase   = (int*)alloc(257 * 4);
    int*   bucketCursor = (int*)alloc(256 * 4);
    int*   csrSrc   = (int*)alloc((size_t)ne * 4);
    unsigned int* A   = (unsigned int*)alloc((size_t)nv * 32 * 4);  // feats(16u) then h2(32u)
    unsigned int* B   = (unsigned int*)alloc((size_t)nv * 32 * 4);  // h1(16u) then h3(32u)
    unsigned int* Z   = (unsigned int*)alloc((size_t)nv * 2 * 4);   // bf16 premultiplied
    uint2* pairs      = (uint2*)alloc((size_t)ne * 8);
    unsigned int* timg = (unsigned int*)alloc((size_t)VOL * 16 * 2);

    auto blocks = [](long long n) { return (int)((n + 255) / 256); };
    const int nbuckets = (nv + 511) >> 9;

    // Image transpose (independent of CSR build)
    k_transpose<<<(GRIDSZ * GRIDSZ * 32 * 4) / 256, 256, 0, stream>>>(img, timg);

    // CSR build: bucket histogram -> scan -> bucketing -> per-bucket sort
    hipMemsetAsync(bucketCount, 0, 256 * 4, stream);
    k_hist<<<(ne + HEPB - 1) / HEPB, 256, 0, stream>>>(edst, bucketCount, ne);
    k_scan256<<<1, 256, 0, stream>>>(bucketCount, bucketBase, bucketCursor, rowStart, nbuckets, nv, ne);
    k_bucket<<<(ne + EPB - 1) / EPB, 256, 0, stream>>>(esrc, edst, bucketCursor, pairs, ne);
    k_binsort<<<nbuckets, 256, 0, stream>>>(pairs, bucketBase, rowStart, invdeg, csrSrc, nv);

    // Features (channel-last bf16 volume) -> bf16 feats
    k_sample<<<blocks((long long)nv * 2), 256, 0, stream>>>(timg, verts, A, nv);

    // Layer 0: 19 -> 32 (fused gather, VPB=256)
    k_gconv<19, 32, 16, true, true, false><<<(nv + 255) / 256, 256, 0, stream>>>(
        A, rowStart, csrSrc, invdeg, ws0, wn0, b0, nullptr, B, nullptr, nv);

    // Layer 1: 32 -> 64 (fused gather, VPB=128)
    k_gconv<32, 64, 16, true, false, false><<<(nv + 127) / 128, 256, 0, stream>>>(
        B, rowStart, csrSrc, invdeg, ws1, wn1, b1, nullptr, A, nullptr, nv);

    // Layer 2: 64 -> 64 (fused gather + premul z = h3 @ Wn3)
    k_gconv<64, 64, 32, true, false, true><<<(nv + 127) / 128, 256, 0, stream>>>(
        A, rowStart, csrSrc, invdeg, ws2, wn2, b2, wn3, B, Z, nv);

    // Layer 3: fused z-gather + final update
    k_final<<<blocks(nv), 256, 0, stream>>>(
        B, Z, rowStart, csrSrc, invdeg, ws3, b3, verts, (float*)d_out, nv);
}